// Round 8
// baseline (201.080 us; speedup 1.0000x reference)
//
#include <hip/hip_runtime.h>
#include <cstddef>

#define BATCH 4
#define CH    16
#define HH    512
#define WW    512
#define HID   128
#define K3    48      // 3*CH
#define YSTR  72      // sY row stride bf16 (64 feat slots + 8 pad); 144 B, b128-aligned reads
#define HSTR  136     // sH row stride (128 + 8 bank-pad), 272 B

typedef __bf16 bf16x8 __attribute__((ext_vector_type(8)));
typedef __bf16 bf16x4 __attribute__((ext_vector_type(4)));
typedef float  f32x4  __attribute__((ext_vector_type(4)));

static __device__ __forceinline__ f32x4 mfma16(bf16x8 a, bf16x8 b, f32x4 c) {
    return __builtin_amdgcn_mfma_f32_16x16x32_bf16(a, b, c, 0, 0, 0);
}

// DPP horizontal neighbors within 16-lane rows (= our pixel groups).
static __device__ __forceinline__ float dpp_left(float v) {
    return __builtin_bit_cast(float, __builtin_amdgcn_update_dpp(
        0, __builtin_bit_cast(int, v), 0x111, 0xF, 0xF, true));
}
static __device__ __forceinline__ float dpp_right(float v) {
    return __builtin_bit_cast(float, __builtin_amdgcn_update_dpp(
        0, __builtin_bit_cast(int, v), 0x101, 0xF, 0xF, true));
}

// ---- prep kernel: write frag-ordered bf16 W0 (+bias col) into d_ws (16 KB).
// Runs once per launch (1 block); the 2048-block main kernel then streams
// its W0 fragments from L2 instead of LDS.
__global__ __launch_bounds__(256)
void ca_prep(const float* __restrict__ w0, const float* __restrict__ b0,
             __bf16* __restrict__ wsb)
{
    const int tid = threadIdx.x;
    for (int e = tid; e < 1024; e += 256) {
        const int ks = e >> 9, rem = e & 511;
        const int t = rem >> 6, ln = rem & 63;
        const int pp = ln & 15, qq = ln >> 4;
        const int o = 16 * t + pp;
        bf16x8 v;
        #pragma unroll
        for (int j = 0; j < 8; ++j) {
            const int k = 32 * ks + 8 * qq + j;
            float val;
            if (k < K3)       val = w0[o * K3 + k];
            else if (k == K3) val = b0[o];
            else              val = 0.f;
            v[j] = (__bf16)val;
        }
        *(bf16x8*)&wsb[e * 8] = v;
    }
}

// v11 = v9 exact (97us: wave-private, barrier-free, DPP stencil, acc[8])
// with the W0 fragment stream moved LDS -> L2:
//  - sW0 (16 KB) deleted; LDS = 4096(sW1)+9216(sY)+17408(sH)+2048(sRU)
//    = 32768 B exactly -> 5 blocks/CU (was 3). Latency-bound kernel
//    (all pipes <31% busy) gets +67% resident waves.
//  - 16 ds_read_b128/wave-seg (~190 of ~400 LDS-pipe cy, the hottest
//    pipe) become coalesced global_load_dwordx4 from an L2-resident
//    16 KB block (VMEM pipe is idle: HBM 13%).
//  - anti-LICM: ws base opaqued per segment via asm "+s" (SGPR base, no
//    per-lane addr re-adds) so the 16 invariant loads can't be hoisted
//    into registers (v6 spill) nor CSE'd.
//  - register pins REMOVED for good: v6 spill / v7 drop / v8+v10 scratch
//    = the RA will not hold these values; stop paying for the attempt.
// launch_bounds (256,4): caps RA at 128 VGPR (safe); if actual <=102 the
// HW grants 5 blocks/CU regardless of the declared minimum.
__global__ __launch_bounds__(256, 4)
void ca_mfma11(const float* __restrict__ x, const __bf16* __restrict__ wsb,
               const float* __restrict__ w1, const float* __restrict__ ru,
               float* __restrict__ out)
{
    __shared__ __align__(16) __bf16 sW1[4 * 64 * 8];       //  4 KB
    __shared__ __align__(16) __bf16 sY[64 * YSTR];         //  9 KB
    __shared__ __align__(16) __bf16 sH[64 * HSTR];         // 17 KB
    __shared__ float sRU[WW];                              //  2 KB  (32768 B total)

    const int tid  = threadIdx.x;
    const int lane = tid & 63;
    const int wv   = tid >> 6;
    const int pxi  = lane & 15;   // pixel index within the wave's 16-px group
    const int cg   = lane >> 4;   // channel group (4 channels); == MFMA quad q
    const int q    = cg;

    // bijective XCD swizzle: XCD k owns rows [256k, 256k+256)
    const int orig = blockIdx.x;
    const int row  = ((orig & 7) << 8) | (orig >> 3);
    const int b    = row >> 9;
    const int i    = row & (HH - 1);

    const size_t plane = (size_t)HH * WW;
    const float* xb    = x + (size_t)b * CH * plane + (size_t)i * WW;
    const bool   up    = (i > 0), dn = (i < HH - 1);
    const int    mypx  = 16 * wv + pxi;

    // own-column stencil: T/M/B per channel; e* = edge columns for lanes
    // pxi==0 (global j-1) / pxi==15 (global j+1)
    float T[4], M[4], B[4];
    float eT[4] = {0,0,0,0}, eM[4] = {0,0,0,0}, eB[4] = {0,0,0,0};

    auto issue_loads = [&](int s) {
        const int j = s * 64 + mypx;
        #pragma unroll
        for (int k = 0; k < 4; ++k) {
            const float* c0 = xb + (size_t)(4 * cg + k) * plane + j;
            T[k] = up ? c0[-WW] : 0.f;
            M[k] =      c0[0];
            B[k] = dn ? c0[WW]  : 0.f;
        }
        if (pxi == 0 || pxi == 15) {
            const int jj = (pxi == 0) ? (j - 1) : (j + 1);
            const bool ok = (jj >= 0) && (jj < WW);
            #pragma unroll
            for (int k = 0; k < 4; ++k) {
                const float* c1 = xb + (size_t)(4 * cg + k) * plane + jj;
                eT[k] = (ok && up) ? c1[-WW] : 0.f;
                eM[k] =  ok        ? c1[0]   : 0.f;
                eB[k] = (ok && dn) ? c1[WW]  : 0.f;
            }
        }
    };

    issue_loads(0);

    // ---- stage W1 [16 x 128] frag-ordered: one entry per thread ----
    {
        const int e = tid;
        const int s = e >> 6, ln = e & 63;
        const int pp = ln & 15, qq = ln >> 4;
        bf16x8 v;
        #pragma unroll
        for (int j = 0; j < 8; ++j)
            v[j] = (__bf16)w1[pp * HID + 32 * s + 8 * qq + j];
        *(bf16x8*)&sW1[e * 8] = v;
    }
    // ---- stage the mask row ----
    for (int e = tid; e < WW; e += 256)
        sRU[e] = ru[(size_t)b * plane + (size_t)i * WW + e];
    // ---- static K-pad of sY: feature 48 = 1.0 (bias), 49..63 = 0 ----
    if (tid < 64) {
        bf16x4 zb = {(__bf16)1.0f, (__bf16)0.f, (__bf16)0.f, (__bf16)0.f};
        bf16x4 zz = {(__bf16)0.f, (__bf16)0.f, (__bf16)0.f, (__bf16)0.f};
        *(bf16x4*)&sY[tid * YSTR + 48] = zb;
        *(bf16x4*)&sY[tid * YSTR + 52] = zz;
        *(bf16x4*)&sY[tid * YSTR + 56] = zz;
        *(bf16x4*)&sY[tid * YSTR + 60] = zz;
    }
    asm volatile("s_waitcnt lgkmcnt(0)");
    __builtin_amdgcn_s_barrier();   // the only barrier in the kernel

    const __bf16* wsp = wsb;

    for (int s = 0; s < 8; ++s) {
        // opaque the weight base each iteration (SGPR pair): defeats LICM/
        // CSE of the 16 invariant fragment loads without touching VGPRs
        asm volatile("" : "+s"(wsp));

        // ---- Sobel via DPP neighbors ----
        float fm[4], fgx[4], fgy[4];
        #pragma unroll
        for (int k = 0; k < 4; ++k) {
            float lT = dpp_left(T[k]),  lM = dpp_left(M[k]),  lB = dpp_left(B[k]);
            float rT = dpp_right(T[k]), rM = dpp_right(M[k]), rB = dpp_right(B[k]);
            if (pxi == 0)  { lT = eT[k]; lM = eM[k]; lB = eB[k]; }
            if (pxi == 15) { rT = eT[k]; rM = eM[k]; rB = eB[k]; }
            fm[k]  = M[k];
            fgx[k] = (rT - lT) + 2.f * (rM - lM) + (rB - lB);
            fgy[k] = (lB - lT) + 2.f * (B[k] - T[k]) + (rB - rT);
        }
        // ---- write features to the wave-private sY row ----
        {
            bf16x4 vm = {(__bf16)fm[0],  (__bf16)fm[1],  (__bf16)fm[2],  (__bf16)fm[3]};
            bf16x4 vx = {(__bf16)fgx[0], (__bf16)fgx[1], (__bf16)fgx[2], (__bf16)fgx[3]};
            bf16x4 vy = {(__bf16)fgy[0], (__bf16)fgy[1], (__bf16)fgy[2], (__bf16)fgy[3]};
            *(bf16x4*)&sY[mypx * YSTR + 4 * cg]          = vm;
            *(bf16x4*)&sY[mypx * YSTR + CH + 4 * cg]     = vx;
            *(bf16x4*)&sY[mypx * YSTR + 2 * CH + 4 * cg] = vy;
        }
        // T/M/B dead -> prefetch next segment (compiler-scheduled)
        if (s < 7) issue_loads(s + 1);

        // ---- MFMA phase (same-wave sY write->read) ----
        const bf16x8 yb0 = *(const bf16x8*)&sY[mypx * YSTR + 8 * q];
        const bf16x8 yb1 = *(const bf16x8*)&sY[mypx * YSTR + 32 + 8 * q];

        const bf16x8* wf = (const bf16x8*)wsp;   // frag e stride = 16 B
        f32x4 acc[8];
        #pragma unroll
        for (int t = 0; t < 8; ++t) {
            const bf16x8 a0 = wf[t * 64 + lane];          // ks=0 frag, L2-hit
            const bf16x8 a1 = wf[(8 + t) * 64 + lane];    // ks=1 frag, L2-hit
            acc[t] = f32x4{0.f, 0.f, 0.f, 0.f};
            acc[t] = mfma16(a0, yb0, acc[t]);
            acc[t] = mfma16(a1, yb1, acc[t]);
        }
        // relu + cvt -> sH[mypx][o], o = 16t + 4q + r (wave-private rows)
        #pragma unroll
        for (int t = 0; t < 8; ++t) {
            bf16x4 hv;
            #pragma unroll
            for (int r = 0; r < 4; ++r)
                hv[r] = (__bf16)fmaxf(acc[t][r], 0.f);
            *(bf16x4*)&sH[mypx * HSTR + 16 * t + 4 * q] = hv;
        }
        // same-wave LDS write->read: no barrier
        f32x4 u = f32x4{0.f, 0.f, 0.f, 0.f};
        #pragma unroll
        for (int ss = 0; ss < 4; ++ss) {
            const bf16x8 hb = *(const bf16x8*)&sH[mypx * HSTR + 32 * ss + 8 * q];
            const bf16x8 aw = *(const bf16x8*)&sW1[(ss * 64 + lane) * 8];
            u = mfma16(aw, hb, u);
        }

        // ---- epilogue: out[c][jg] = fm[r] + u[r]*mask, c = 4q + r ----
        const int jg = s * 64 + mypx;
        const float rv = sRU[jg];
        const float m  = (rv > 0.5f) ? 1.f : 0.f;
        float* ob = out + (size_t)b * CH * plane + (size_t)i * WW + jg;
        #pragma unroll
        for (int r = 0; r < 4; ++r) {
            const int c = 4 * q + r;
            ob[(size_t)c * plane] = fmaf(u[r], m, fm[r]);
        }
    }
}

extern "C" void kernel_launch(void* const* d_in, const int* in_sizes, int n_in,
                              void* d_out, int out_size, void* d_ws, size_t ws_size,
                              hipStream_t stream) {
    const float* x  = (const float*)d_in[0];
    const float* w0 = (const float*)d_in[1];
    const float* b0 = (const float*)d_in[2];
    const float* w1 = (const float*)d_in[3];
    const float* ru = (const float*)d_in[4];
    float* out = (float*)d_out;
    __bf16* wsb = (__bf16*)d_ws;   // 16 KB frag-ordered W0(+bias)

    hipLaunchKernelGGL(ca_prep, dim3(1), dim3(256), 0, stream, w0, b0, wsb);
    dim3 grid(BATCH * HH);   // 2048 blocks: one per (batch, image row)
    dim3 block(256);
    hipLaunchKernelGGL(ca_mfma11, grid, block, 0, stream, x, wsb, w1, ru, out);
}